// Round 1
// baseline (68.954 us; speedup 1.0000x reference)
//
#include <hip/hip_runtime.h>
#include <math.h>

// Problem constants (fixed by setup_inputs: B=64, HW=6400 (80x80), C=85, T=50)
constexpr int B_  = 64;
constexpr int HW_ = 6400;
constexpr int C_  = 85;
constexpr int T_  = 50;
constexpr int H_  = 80;
constexpr int W_  = 80;
constexpr float LC   = 5.0f;   // LAMBDA_COORD
constexpr float LN   = 0.5f;   // LAMBDA_NOOBJ
constexpr float INV_N = 1.0f / (B_ * T_);   // 1/num_objects
constexpr int SUB   = 8;            // blocks per image in noobj pass
constexpr int CHUNK = HW_ / SUB;    // 800 cells per block

// ws layout
constexpr size_t MASK_BYTES = (size_t)B_ * HW_;      // 409600, byte mask
constexpr size_t OFF_SUM    = MASK_BYTES;            // float[64]
constexpr size_t OFF_CNT    = MASK_BYTES + 256;      // int[64]
constexpr size_t WS_USED    = MASK_BYTES + 512;

__device__ __forceinline__ float softplus_f(float x) {
    // numerically stable log(1 + e^x)
    return fmaxf(x, 0.0f) + log1pf(expf(-fabsf(x)));
}

// One 64-lane wave per object. Lane l holds channel l and channel l+64.
__global__ __launch_bounds__(256) void obj_kernel(
    const float* __restrict__ pred, const float* __restrict__ tbox,
    const int* __restrict__ tcls, float* __restrict__ out,
    unsigned char* __restrict__ mask)
{
    int gid  = blockIdx.x * blockDim.x + threadIdx.x;
    int obj  = gid >> 6;            // wave id = object id
    int lane = threadIdx.x & 63;
    if (obj >= B_ * T_) return;
    int b = obj / T_;

    const float4 tb = ((const float4*)tbox)[obj];   // cx, cy, w, h
    float gxf = floorf(tb.x * (float)W_);
    float gyf = floorf(tb.y * (float)H_);
    int gi = (int)(gyf * (float)W_ + gxf);
    if (lane == 0) mask[b * HW_ + gi] = 1;          // idempotent (dups OK)

    const float* g = pred + ((size_t)b * HW_ + gi) * C_;
    int cls = tcls[obj];

    int   c2 = lane + 64;
    float v1 = g[lane];
    float v2 = (c2 < C_) ? g[c2] : 0.0f;

    // logsumexp over class channels 5..84
    float m = -1e30f;
    if (lane >= 5) m = v1;
    if (c2 < C_)   m = fmaxf(m, v2);
    #pragma unroll
    for (int off = 32; off; off >>= 1) m = fmaxf(m, __shfl_xor(m, off, 64));
    float s = 0.0f;
    if (lane >= 5) s += expf(v1 - m);
    if (c2 < C_)   s += expf(v2 - m);
    #pragma unroll
    for (int off = 32; off; off >>= 1) s += __shfl_xor(s, off, 64);
    float lse = m + logf(s);

    float contrib = 0.0f;
    if (lane == 0) {          // x: mean over 2 comps -> 0.5 each, * LAMBDA_COORD
        float d = 1.0f / (1.0f + expf(-v1)) - (tb.x * (float)W_ - gxf);
        contrib = LC * 0.5f * d * d;
    } else if (lane == 1) {
        float d = 1.0f / (1.0f + expf(-v1)) - (tb.y * (float)H_ - gyf);
        contrib = LC * 0.5f * d * d;
    } else if (lane == 2) {
        float d = v1 - logf(tb.z * (float)W_ + 1e-16f);
        contrib = LC * 0.5f * d * d;
    } else if (lane == 3) {
        float d = v1 - logf(tb.w * (float)H_ + 1e-16f);
        contrib = LC * 0.5f * d * d;
    } else if (lane == 4) {
        contrib = softplus_f(-v1);          // BCE with target 1
    }
    if (lane == 5 + cls) contrib += lse - v1;   // class CE
    if (c2   == 5 + cls) contrib += lse - v2;

    #pragma unroll
    for (int off = 32; off; off >>= 1) contrib += __shfl_xor(contrib, off, 64);
    if (lane == 0) atomicAdd(out, contrib * INV_N);
}

// 8 blocks per image; each reduces softplus(conf) + count over no-object cells.
__global__ __launch_bounds__(256) void noobj_partial(
    const float* __restrict__ pred, const unsigned char* __restrict__ mask,
    float* __restrict__ img_sum, int* __restrict__ img_cnt)
{
    int b    = blockIdx.x / SUB;
    int sub  = blockIdx.x % SUB;
    int base = sub * CHUNK;
    const float* p = pred + (size_t)b * HW_ * C_;
    const unsigned char* mk = mask + b * HW_;

    float sum = 0.0f;
    int   cnt = 0;
    for (int i = base + (int)threadIdx.x; i < base + CHUNK; i += 256) {
        float conf = p[(size_t)i * C_ + 4];
        if (!mk[i]) { sum += softplus_f(conf); cnt++; }
    }
    #pragma unroll
    for (int off = 32; off; off >>= 1) {
        sum += __shfl_xor(sum, off, 64);
        cnt += __shfl_xor(cnt, off, 64);
    }
    __shared__ float ss[4];
    __shared__ int   sc[4];
    int wid = threadIdx.x >> 6;
    if ((threadIdx.x & 63) == 0) { ss[wid] = sum; sc[wid] = cnt; }
    __syncthreads();
    if (threadIdx.x == 0) {
        float S  = ss[0] + ss[1] + ss[2] + ss[3];
        int   Cc = sc[0] + sc[1] + sc[2] + sc[3];
        atomicAdd(&img_sum[b], S);
        atomicAdd(&img_cnt[b], Cc);
    }
}

// One wave: lane t = image t. term = 0.5 * sum/max(cnt,1); reduce; add.
__global__ __launch_bounds__(64) void finalize_k(
    const float* __restrict__ img_sum, const int* __restrict__ img_cnt,
    float* __restrict__ out)
{
    int t = threadIdx.x;
    float term = LN * img_sum[t] / (float)max(img_cnt[t], 1);
    #pragma unroll
    for (int off = 32; off; off >>= 1) term += __shfl_xor(term, off, 64);
    if (t == 0) atomicAdd(out, term * INV_N);
}

extern "C" void kernel_launch(void* const* d_in, const int* in_sizes, int n_in,
                              void* d_out, int out_size, void* d_ws, size_t ws_size,
                              hipStream_t stream) {
    const float* pred = (const float*)d_in[0];
    const float* tbox = (const float*)d_in[1];
    const int*   tcls = (const int*)d_in[2];
    float* out = (float*)d_out;

    unsigned char* mask    = (unsigned char*)d_ws;
    float*         img_sum = (float*)((char*)d_ws + OFF_SUM);
    int*           img_cnt = (int*)((char*)d_ws + OFF_CNT);

    // zero output accumulator + mask + per-image accumulators (ws is poisoned)
    hipMemsetAsync(out, 0, sizeof(float), stream);
    hipMemsetAsync(d_ws, 0, WS_USED, stream);

    // per-object losses + mask marking: 3200 waves, 4 waves/block
    int nwaves = B_ * T_;
    obj_kernel<<<(nwaves * 64 + 255) / 256, 256, 0, stream>>>(pred, tbox, tcls, out, mask);

    // no-object BCE partial sums
    noobj_partial<<<B_ * SUB, 256, 0, stream>>>(pred, mask, img_sum, img_cnt);

    // per-image division + final accumulation
    finalize_k<<<1, 64, 0, stream>>>(img_sum, img_cnt, out);
}

// Round 2
// 23.094 us; speedup vs baseline: 2.9859x; 2.9859x over previous
//
#include <hip/hip_runtime.h>
#include <math.h>

// Problem constants (fixed by setup_inputs: B=64, HW=6400 (80x80), C=85, T=50)
constexpr int B_  = 64;
constexpr int HW_ = 6400;
constexpr int C_  = 85;
constexpr int T_  = 50;
constexpr int H_  = 80;
constexpr int W_  = 80;
constexpr float LC    = 5.0f;              // LAMBDA_COORD
constexpr float LN    = 0.5f;              // LAMBDA_NOOBJ
constexpr float INV_N = 1.0f / (B_ * T_);  // 1/num_objects
constexpr int SUBN  = 4;                   // conf-sum blocks per image
constexpr int CHUNK = HW_ / SUBN;          // 1600 cells per block

// ws layout (floats) — every word is written each call before it is read,
// so no memset / poison-clearing is ever needed.
constexpr int OFF_PEROBJ = 0;                    // [3200] per-object loss
constexpr int OFF_MSP    = OFF_PEROBJ + B_ * T_; // [3200] softplus(conf) if canonical else 0
constexpr int OFF_CANON  = OFF_MSP + B_ * T_;    // [3200] 1.0 if canonical else 0
constexpr int OFF_PART   = OFF_CANON + B_ * T_;  // [256]  per-(image,sub) conf softplus sums
constexpr int OFF_IMG    = OFF_PART + B_ * SUBN; // [64]   per-image result

__device__ __forceinline__ float softplus_f(float x) {
    return fmaxf(x, 0.0f) + log1pf(expf(-fabsf(x)));   // stable log(1+e^x)
}

// One 64-lane wave per object. Lane l holds channels l and l+64.
__global__ __launch_bounds__(256) void obj_kernel(
    const float* __restrict__ pred, const float* __restrict__ tbox,
    const int* __restrict__ tcls,
    float* __restrict__ per_obj, float* __restrict__ masked_sp,
    float* __restrict__ canon)
{
    int gid  = blockIdx.x * blockDim.x + threadIdx.x;
    int obj  = gid >> 6;
    int lane = threadIdx.x & 63;
    if (obj >= B_ * T_) return;
    int b   = obj / T_;
    int myt = obj % T_;

    const float4 tb = ((const float4*)tbox)[obj];   // cx, cy, w, h
    float gxf = floorf(tb.x * (float)W_);
    float gyf = floorf(tb.y * (float)H_);
    int gi = (int)(gyf * (float)W_ + gxf);

    // canonical = no earlier object in this image occupies the same cell
    bool dup = false;
    if (lane < T_) {
        const float4 to = ((const float4*)tbox)[b * T_ + lane];
        int gio = (int)(floorf(to.y * (float)H_) * (float)W_ +
                        floorf(to.x * (float)W_));
        dup = (lane < myt) && (gio == gi);
    }
    bool canonical = (__ballot(dup) == 0ULL);

    const float* g = pred + ((size_t)b * HW_ + gi) * C_;
    int cls = tcls[obj];

    int   c2 = lane + 64;
    float v1 = g[lane];
    float v2 = (c2 < C_) ? g[c2] : 0.0f;

    // logsumexp over class channels 5..84
    float m = -1e30f;
    if (lane >= 5) m = v1;
    if (c2 < C_)   m = fmaxf(m, v2);
    #pragma unroll
    for (int off = 32; off; off >>= 1) m = fmaxf(m, __shfl_xor(m, off, 64));
    float s = 0.0f;
    if (lane >= 5) s += expf(v1 - m);
    if (c2 < C_)   s += expf(v2 - m);
    #pragma unroll
    for (int off = 32; off; off >>= 1) s += __shfl_xor(s, off, 64);
    float lse = m + logf(s);

    float contrib = 0.0f;
    if (lane == 0) {          // xy: mean over 2 comps -> 0.5 each, * LAMBDA_COORD
        float d = 1.0f / (1.0f + expf(-v1)) - (tb.x * (float)W_ - gxf);
        contrib = LC * 0.5f * d * d;
    } else if (lane == 1) {
        float d = 1.0f / (1.0f + expf(-v1)) - (tb.y * (float)H_ - gyf);
        contrib = LC * 0.5f * d * d;
    } else if (lane == 2) {
        float d = v1 - logf(tb.z * (float)W_ + 1e-16f);
        contrib = LC * 0.5f * d * d;
    } else if (lane == 3) {
        float d = v1 - logf(tb.w * (float)H_ + 1e-16f);
        contrib = LC * 0.5f * d * d;
    } else if (lane == 4) {
        contrib = softplus_f(-v1);                   // objectness BCE, target 1
        masked_sp[obj] = canonical ? softplus_f(v1) : 0.0f;
    }
    if (lane == 5 + cls) contrib += lse - v1;        // class CE
    if (c2   == 5 + cls) contrib += lse - v2;

    #pragma unroll
    for (int off = 32; off; off >>= 1) contrib += __shfl_xor(contrib, off, 64);
    if (lane == 0) {
        per_obj[obj] = contrib;
        canon[obj]   = canonical ? 1.0f : 0.0f;
    }
}

// Per-image softplus(conf) total over ALL cells (no mask). 4 blocks/image.
__global__ __launch_bounds__(256) void conf_partial(
    const float* __restrict__ pred, float* __restrict__ img_part)
{
    int b    = blockIdx.x / SUBN;
    int sub  = blockIdx.x % SUBN;
    int base = sub * CHUNK;
    const float* p = pred + (size_t)b * HW_ * C_;

    float sum = 0.0f;
    for (int i = base + (int)threadIdx.x; i < base + CHUNK; i += 256)
        sum += softplus_f(p[(size_t)i * C_ + 4]);
    #pragma unroll
    for (int off = 32; off; off >>= 1) sum += __shfl_xor(sum, off, 64);

    __shared__ float ss[4];
    int wid = threadIdx.x >> 6;
    if ((threadIdx.x & 63) == 0) ss[wid] = sum;
    __syncthreads();
    if (threadIdx.x == 0)
        img_part[blockIdx.x] = ss[0] + ss[1] + ss[2] + ss[3];
}

// One wave per image: combine per-object losses + no-object term.
__global__ __launch_bounds__(64) void per_image(
    const float* __restrict__ per_obj, const float* __restrict__ masked_sp,
    const float* __restrict__ canon, const float* __restrict__ img_part,
    float* __restrict__ img_result)
{
    int b = blockIdx.x;
    int t = threadIdx.x;

    float po  = (t < T_)   ? per_obj[b * T_ + t]    : 0.0f;
    float msp = (t < T_)   ? masked_sp[b * T_ + t]  : 0.0f;
    float cn  = (t < T_)   ? canon[b * T_ + t]      : 0.0f;
    float tp  = (t < SUBN) ? img_part[b * SUBN + t] : 0.0f;
    #pragma unroll
    for (int off = 32; off; off >>= 1) {
        po  += __shfl_xor(po,  off, 64);
        msp += __shfl_xor(msp, off, 64);
        cn  += __shfl_xor(cn,  off, 64);
        tp  += __shfl_xor(tp,  off, 64);
    }
    if (t == 0) {
        float n_noobj = fmaxf((float)HW_ - cn, 1.0f);
        float noobj   = LN * (tp - msp) / n_noobj;
        img_result[b] = po + noobj;
    }
}

// One wave: reduce the 64 per-image results, plain store (no pre-zero of out).
__global__ __launch_bounds__(64) void final_k(
    const float* __restrict__ img_result, float* __restrict__ out)
{
    float v = img_result[threadIdx.x];
    #pragma unroll
    for (int off = 32; off; off >>= 1) v += __shfl_xor(v, off, 64);
    if (threadIdx.x == 0) out[0] = v * INV_N;
}

extern "C" void kernel_launch(void* const* d_in, const int* in_sizes, int n_in,
                              void* d_out, int out_size, void* d_ws, size_t ws_size,
                              hipStream_t stream) {
    const float* pred = (const float*)d_in[0];
    const float* tbox = (const float*)d_in[1];
    const int*   tcls = (const int*)d_in[2];
    float* out = (float*)d_out;

    float* ws        = (float*)d_ws;
    float* per_obj   = ws + OFF_PEROBJ;
    float* masked_sp = ws + OFF_MSP;
    float* canon     = ws + OFF_CANON;
    float* img_part  = ws + OFF_PART;
    float* img_res   = ws + OFF_IMG;

    obj_kernel  <<<(B_ * T_ * 64 + 255) / 256, 256, 0, stream>>>(
        pred, tbox, tcls, per_obj, masked_sp, canon);
    conf_partial<<<B_ * SUBN, 256, 0, stream>>>(pred, img_part);
    per_image   <<<B_, 64, 0, stream>>>(per_obj, masked_sp, canon, img_part, img_res);
    final_k     <<<1, 64, 0, stream>>>(img_res, out);
}

// Round 3
// 19.956 us; speedup vs baseline: 3.4553x; 1.1572x over previous
//
#include <hip/hip_runtime.h>
#include <math.h>

// Problem constants (fixed by setup_inputs: B=64, HW=6400 (80x80), C=85, T=50)
constexpr int B_  = 64;
constexpr int HW_ = 6400;
constexpr int C_  = 85;
constexpr int T_  = 50;
constexpr int H_  = 80;
constexpr int W_  = 80;
constexpr float LC    = 5.0f;              // LAMBDA_COORD
constexpr float LN    = 0.5f;              // LAMBDA_NOOBJ
constexpr float INV_N = 1.0f / (B_ * T_);  // 1/num_objects

constexpr int OBJ_BLOCKS  = (B_ * T_) / 4;   // 800: 4 waves/block, 1 wave/object
constexpr int SUBN        = 16;              // conf blocks per image
constexpr int CONF_BLOCKS = B_ * SUBN;       // 1024
constexpr int CHUNK       = HW_ / SUBN;      // 400 cells per conf block

// ws layout (floats) — every word written each call before read: no memsets.
constexpr int OFF_PEROBJ = 0;                    // [3200] per-object loss
constexpr int OFF_MSP    = OFF_PEROBJ + B_ * T_; // [3200] softplus(conf) if canonical
constexpr int OFF_CANON  = OFF_MSP + B_ * T_;    // [3200] 1.0 if canonical
constexpr int OFF_PART   = OFF_CANON + B_ * T_;  // [1024] per-(image,sub) conf sums

__device__ __forceinline__ float softplus_f(float x) {
    return fmaxf(x, 0.0f) + log1pf(expf(-fabsf(x)));   // stable log(1+e^x)
}

// Fused: blocks [0, OBJ_BLOCKS) = per-object waves;
//        blocks [OBJ_BLOCKS, OBJ_BLOCKS+CONF_BLOCKS) = conf softplus scan.
__global__ __launch_bounds__(256) void main_kernel(
    const float* __restrict__ pred, const float* __restrict__ tbox,
    const int* __restrict__ tcls,
    float* __restrict__ per_obj, float* __restrict__ masked_sp,
    float* __restrict__ canon, float* __restrict__ img_part)
{
    if (blockIdx.x < OBJ_BLOCKS) {
        // ---- per-object path: one 64-lane wave per object ----
        int gid  = blockIdx.x * 256 + threadIdx.x;
        int obj  = gid >> 6;
        int lane = threadIdx.x & 63;
        int b   = obj / T_;
        int myt = obj % T_;

        const float4 tb = ((const float4*)tbox)[obj];   // cx, cy, w, h
        float gxf = floorf(tb.x * (float)W_);
        float gyf = floorf(tb.y * (float)H_);
        int gi = (int)(gyf * (float)W_ + gxf);

        // canonical = no earlier object in this image occupies the same cell
        bool dup = false;
        if (lane < T_) {
            const float4 to = ((const float4*)tbox)[b * T_ + lane];
            int gio = (int)(floorf(to.y * (float)H_) * (float)W_ +
                            floorf(to.x * (float)W_));
            dup = (lane < myt) && (gio == gi);
        }
        bool canonical = (__ballot(dup) == 0ULL);

        const float* g = pred + ((size_t)b * HW_ + gi) * C_;
        int cls = tcls[obj];

        int   c2 = lane + 64;
        float v1 = g[lane];
        float v2 = (c2 < C_) ? g[c2] : 0.0f;

        // logsumexp over class channels 5..84
        float m = -1e30f;
        if (lane >= 5) m = v1;
        if (c2 < C_)   m = fmaxf(m, v2);
        #pragma unroll
        for (int off = 32; off; off >>= 1) m = fmaxf(m, __shfl_xor(m, off, 64));
        float s = 0.0f;
        if (lane >= 5) s += expf(v1 - m);
        if (c2 < C_)   s += expf(v2 - m);
        #pragma unroll
        for (int off = 32; off; off >>= 1) s += __shfl_xor(s, off, 64);
        float lse = m + logf(s);

        float contrib = 0.0f;
        if (lane == 0) {          // xy: mean over 2 comps -> 0.5 each, * LC
            float d = 1.0f / (1.0f + expf(-v1)) - (tb.x * (float)W_ - gxf);
            contrib = LC * 0.5f * d * d;
        } else if (lane == 1) {
            float d = 1.0f / (1.0f + expf(-v1)) - (tb.y * (float)H_ - gyf);
            contrib = LC * 0.5f * d * d;
        } else if (lane == 2) {
            float d = v1 - logf(tb.z * (float)W_ + 1e-16f);
            contrib = LC * 0.5f * d * d;
        } else if (lane == 3) {
            float d = v1 - logf(tb.w * (float)H_ + 1e-16f);
            contrib = LC * 0.5f * d * d;
        } else if (lane == 4) {
            contrib = softplus_f(-v1);                   // objectness BCE
            masked_sp[obj] = canonical ? softplus_f(v1) : 0.0f;
        }
        if (lane == 5 + cls) contrib += lse - v1;        // class CE
        if (c2   == 5 + cls) contrib += lse - v2;

        #pragma unroll
        for (int off = 32; off; off >>= 1) contrib += __shfl_xor(contrib, off, 64);
        if (lane == 0) {
            per_obj[obj] = contrib;
            canon[obj]   = canonical ? 1.0f : 0.0f;
        }
    } else {
        // ---- conf softplus scan over ALL cells (no mask) ----
        int c    = blockIdx.x - OBJ_BLOCKS;
        int b    = c >> 4;          // c / SUBN
        int sub  = c & 15;          // c % SUBN
        int base = sub * CHUNK;
        const float* p = pred + (size_t)b * HW_ * C_;

        float sum = 0.0f;
        for (int i = base + (int)threadIdx.x; i < base + CHUNK; i += 256)
            sum += softplus_f(p[(size_t)i * C_ + 4]);
        #pragma unroll
        for (int off = 32; off; off >>= 1) sum += __shfl_xor(sum, off, 64);

        __shared__ float ss[4];
        int wid = threadIdx.x >> 6;
        if ((threadIdx.x & 63) == 0) ss[wid] = sum;
        __syncthreads();
        if (threadIdx.x == 0)
            img_part[c] = ss[0] + ss[1] + ss[2] + ss[3];
    }
}

// One 256-thread block: 4 threads per image fold 50 objects + 16 conf parts,
// then a single wave reduces the 64 image results and stores out[0].
__global__ __launch_bounds__(256) void combine_kernel(
    const float* __restrict__ per_obj, const float* __restrict__ masked_sp,
    const float* __restrict__ canon, const float* __restrict__ img_part,
    float* __restrict__ out)
{
    int t = threadIdx.x;
    int b = t >> 2;      // image
    int q = t & 3;       // quarter

    float po = 0.0f, msp = 0.0f, cn = 0.0f, tp = 0.0f;
    for (int i = q; i < T_; i += 4) {
        po  += per_obj[b * T_ + i];
        msp += masked_sp[b * T_ + i];
        cn  += canon[b * T_ + i];
    }
    for (int j = q; j < SUBN; j += 4)
        tp += img_part[b * SUBN + j];

    // fold the 4-lane group (lanes b*4..b*4+3 are contiguous within a wave)
    #pragma unroll
    for (int off = 1; off <= 2; off <<= 1) {
        po  += __shfl_xor(po,  off, 64);
        msp += __shfl_xor(msp, off, 64);
        cn  += __shfl_xor(cn,  off, 64);
        tp  += __shfl_xor(tp,  off, 64);
    }

    __shared__ float simg[B_];
    if (q == 0) {
        float n_noobj = fmaxf((float)HW_ - cn, 1.0f);
        simg[b] = po + LN * (tp - msp) / n_noobj;
    }
    __syncthreads();

    if (t < 64) {
        float v = simg[t];
        #pragma unroll
        for (int off = 32; off; off >>= 1) v += __shfl_xor(v, off, 64);
        if (t == 0) out[0] = v * INV_N;
    }
}

extern "C" void kernel_launch(void* const* d_in, const int* in_sizes, int n_in,
                              void* d_out, int out_size, void* d_ws, size_t ws_size,
                              hipStream_t stream) {
    const float* pred = (const float*)d_in[0];
    const float* tbox = (const float*)d_in[1];
    const int*   tcls = (const int*)d_in[2];
    float* out = (float*)d_out;

    float* ws        = (float*)d_ws;
    float* per_obj   = ws + OFF_PEROBJ;
    float* masked_sp = ws + OFF_MSP;
    float* canon     = ws + OFF_CANON;
    float* img_part  = ws + OFF_PART;

    main_kernel<<<OBJ_BLOCKS + CONF_BLOCKS, 256, 0, stream>>>(
        pred, tbox, tcls, per_obj, masked_sp, canon, img_part);
    combine_kernel<<<1, 256, 0, stream>>>(per_obj, masked_sp, canon, img_part, out);
}